// Round 1
// baseline (187.676 us; speedup 1.0000x reference)
//
#include <hip/hip_runtime.h>

#define B_    16
#define CIN_  128
#define COUT_ 128
#define N_    4096
#define K_    16

// ---------------------------------------------------------------------------
// Kernel 1: h[b][n][co] = relu( sum_ci W[co][ci] * x[b][ci][n] )
// Block: 256 threads, tile = 64 co  x 64 n, b fixed.
// LDS: xs[128 ci][64 n] (32 KB) + wt (W transposed, quad-swizzled, 32 KB).
// Thread (q = tid&15 -> co quad, g = tid>>4 -> n quad): 4co x 4n accumulators.
// ---------------------------------------------------------------------------
__global__ __launch_bounds__(256) void gemm_relu_k(
    const float* __restrict__ x, const float* __restrict__ W,
    float* __restrict__ h) {
  __shared__ float xs[128 * 64];  // [ci][n]
  __shared__ float wt[128 * 64];  // [ci][swizzled co]
  const int tid = threadIdx.x;
  const int n0  = blockIdx.x * 64;
  const int co0 = blockIdx.y * 64;
  const int b   = blockIdx.z;

  // ---- stage x tile [128 ci][64 n], coalesced float4 loads ----
  {
    const float4* xg = reinterpret_cast<const float4*>(
        x + (size_t)b * CIN_ * N_ + n0);
#pragma unroll
    for (int r = 0; r < 8; ++r) {
      int id = tid + 256 * r;     // 0..2047
      int ci = id >> 4;           // 0..127
      int nq = id & 15;           // 0..15 (float4 within 64 n)
      float4 v = xg[(size_t)ci * (N_ / 4) + nq];
      *reinterpret_cast<float4*>(&xs[ci * 64 + 4 * nq]) = v;
    }
  }
  // ---- stage W half rows [co0..co0+63], transposed with quad swizzle ----
  // element W[co0+co_l][ci] stored at wt[ci*64 + (((co_l>>2)+(ci>>2))&15)*4 + (co_l&3)]
  {
    const float4* wg = reinterpret_cast<const float4*>(W + (size_t)co0 * CIN_);
#pragma unroll
    for (int r = 0; r < 8; ++r) {
      int co_l = (tid >> 5) + 8 * r;  // 0..63
      int ciq  = tid & 31;            // ci quad 0..31
      float4 v = wg[co_l * 32 + ciq];
      int qq = co_l >> 2, c = co_l & 3;
      int col = (((qq + ciq) & 15) << 2) | c;
      wt[(4 * ciq + 0) * 64 + col] = v.x;
      wt[(4 * ciq + 1) * 64 + col] = v.y;
      wt[(4 * ciq + 2) * 64 + col] = v.z;
      wt[(4 * ciq + 3) * 64 + col] = v.w;
    }
  }
  __syncthreads();

  const int q = tid & 15;   // co quad: co = co0 + 4q .. +3
  const int g = tid >> 4;   // n quad : n  = n0 + 4g .. +3
  float4 a0 = {0.f, 0.f, 0.f, 0.f};
  float4 a1 = a0, a2 = a0, a3 = a0;

#pragma unroll 8
  for (int ci = 0; ci < 128; ++ci) {
    int col = ((q + (ci >> 2)) & 15) << 2;
    float4 wv = *reinterpret_cast<const float4*>(&wt[ci * 64 + col]);
    float4 xv = *reinterpret_cast<const float4*>(&xs[ci * 64 + 4 * g]);
    a0.x += wv.x * xv.x; a0.y += wv.y * xv.x; a0.z += wv.z * xv.x; a0.w += wv.w * xv.x;
    a1.x += wv.x * xv.y; a1.y += wv.y * xv.y; a1.z += wv.z * xv.y; a1.w += wv.w * xv.y;
    a2.x += wv.x * xv.z; a2.y += wv.y * xv.z; a2.z += wv.z * xv.z; a2.w += wv.w * xv.z;
    a3.x += wv.x * xv.w; a3.y += wv.y * xv.w; a3.z += wv.z * xv.w; a3.w += wv.w * xv.w;
  }

  // ---- ReLU + store h[b][n][co] (co contiguous), coalesced float4 ----
  float* hp = h + ((size_t)b * N_ + (n0 + 4 * g)) * COUT_ + co0 + 4 * q;
  float4 r0, r1, r2, r3;
  r0.x = fmaxf(a0.x, 0.f); r0.y = fmaxf(a0.y, 0.f); r0.z = fmaxf(a0.z, 0.f); r0.w = fmaxf(a0.w, 0.f);
  r1.x = fmaxf(a1.x, 0.f); r1.y = fmaxf(a1.y, 0.f); r1.z = fmaxf(a1.z, 0.f); r1.w = fmaxf(a1.w, 0.f);
  r2.x = fmaxf(a2.x, 0.f); r2.y = fmaxf(a2.y, 0.f); r2.z = fmaxf(a2.z, 0.f); r2.w = fmaxf(a2.w, 0.f);
  r3.x = fmaxf(a3.x, 0.f); r3.y = fmaxf(a3.y, 0.f); r3.z = fmaxf(a3.z, 0.f); r3.w = fmaxf(a3.w, 0.f);
  *reinterpret_cast<float4*>(hp + 0 * COUT_) = r0;
  *reinterpret_cast<float4*>(hp + 1 * COUT_) = r1;
  *reinterpret_cast<float4*>(hp + 2 * COUT_) = r2;
  *reinterpret_cast<float4*>(hp + 3 * COUT_) = r3;
}

// ---------------------------------------------------------------------------
// Kernel 2: out[b][co][n] = (1/17)*(sum_k h[b][idx[b,n,k]][co] + h[b][n][co]) + bias[co]
// Block: 256 threads, tile = 64 n x 128 co, b fixed.
// Thread (q = tid&31 -> co quad of 128, g = tid>>5 -> 8 n each).
// Gathers: lanes span co -> 2x512B coalesced reads per (n,k), mostly L2 hits.
// Output transposed through padded LDS for coalesced stores.
// ---------------------------------------------------------------------------
__global__ __launch_bounds__(256) void aggr_k(
    const float* __restrict__ h, const int* __restrict__ ei,
    const float* __restrict__ bias, float* __restrict__ out) {
  __shared__ int   idx_s[64 * 16];
  __shared__ float res_s[64 * 129];  // [n][co], pad 129 -> conflict-free n-lane reads
  const int tid = threadIdx.x;
  const int n0  = blockIdx.x * 64;
  const int b   = blockIdx.y;

  // ---- stage neighbor indices for 64 nodes (coalesced int4) ----
  {
    const int4* src =
        reinterpret_cast<const int4*>(ei + ((size_t)b * N_ + n0) * K_);
    reinterpret_cast<int4*>(idx_s)[tid] = src[tid];
  }
  __syncthreads();

  const int q = tid & 31;   // co = 4q .. 4q+3
  const int g = tid >> 5;   // n_local = 8g .. 8g+7
  const float* hb = h + (size_t)b * N_ * COUT_;
  const float4 bv = *reinterpret_cast<const float4*>(&bias[4 * q]);

  float4 acc[8];
#pragma unroll
  for (int j = 0; j < 8; ++j) {  // self-loop term
    int n = 8 * g + j;
    acc[j] = *reinterpret_cast<const float4*>(
        &hb[(size_t)(n0 + n) * COUT_ + 4 * q]);
  }
#pragma unroll 4
  for (int k = 0; k < K_; ++k) {
#pragma unroll
    for (int j = 0; j < 8; ++j) {
      int n  = 8 * g + j;
      int jj = idx_s[n * K_ + k];
      float4 v = *reinterpret_cast<const float4*>(
          &hb[(size_t)jj * COUT_ + 4 * q]);
      acc[j].x += v.x; acc[j].y += v.y; acc[j].z += v.z; acc[j].w += v.w;
    }
  }

  const float norm = 1.0f / 17.0f;
#pragma unroll
  for (int j = 0; j < 8; ++j) {
    int n = 8 * g + j;
    float4 r;
    r.x = acc[j].x * norm + bv.x;
    r.y = acc[j].y * norm + bv.y;
    r.z = acc[j].z * norm + bv.z;
    r.w = acc[j].w * norm + bv.w;
    res_s[n * 129 + 4 * q + 0] = r.x;
    res_s[n * 129 + 4 * q + 1] = r.y;
    res_s[n * 129 + 4 * q + 2] = r.z;
    res_s[n * 129 + 4 * q + 3] = r.w;
  }
  __syncthreads();

  // ---- transposed write-out: lanes along n -> coalesced 256B stores ----
#pragma unroll
  for (int i = 0; i < 32; ++i) {
    int flat = i * 256 + tid;   // 0..8191
    int co = flat >> 6;         // 0..127
    int n  = flat & 63;
    out[(size_t)(b * COUT_ + co) * N_ + n0 + n] = res_s[n * 129 + co];
  }
}

extern "C" void kernel_launch(void* const* d_in, const int* in_sizes, int n_in,
                              void* d_out, int out_size, void* d_ws, size_t ws_size,
                              hipStream_t stream) {
  const float* x    = (const float*)d_in[0];
  const int*   ei   = (const int*)d_in[1];   // [2][B][N][K]; we use plane 0
  const float* W    = (const float*)d_in[2];
  const float* bias = (const float*)d_in[3];
  float* out = (float*)d_out;
  float* h   = (float*)d_ws;   // needs B*N*COUT*4 = 32 MB scratch

  gemm_relu_k<<<dim3(N_ / 64, COUT_ / 64, B_), 256, 0, stream>>>(x, W, h);
  aggr_k<<<dim3(N_ / 64, B_), 256, 0, stream>>>(h, ei, bias, out);
}

// Round 2
// 124.151 us; speedup vs baseline: 1.5117x; 1.5117x over previous
//
#include <hip/hip_runtime.h>

#define B_    16
#define CIN_  128
#define COUT_ 128
#define N_    4096
#define K_    16

typedef __attribute__((ext_vector_type(8))) short bf16x8;  // 8 bf16 = 4 VGPR
typedef __attribute__((ext_vector_type(4))) float f32x4;

__device__ inline unsigned short f2bf(float f) {  // round-to-nearest-even
  unsigned u = __float_as_uint(f);
  u += 0x7fffu + ((u >> 16) & 1u);
  return (unsigned short)(u >> 16);
}

// XCD-affinity swizzle: dispatch is round-robin over 8 XCDs by linear block id,
// so pin batch b to XCD b>>1 -> each XCD's 4MB L2 holds exactly 2 batches of h
// (2 x 2MB bf16). Bijective: l = (slot<<3)|xcd, slot = (hi<<6)|ntile.
__device__ inline void swizzle(int l, int& b, int& n0) {
  int xcd = l & 7, slot = l >> 3;
  b  = (xcd << 1) | (slot >> 6);
  n0 = (slot & 63) * 64;
}

// ---------------------------------------------------------------------------
// Kernel 1: h[b][n][co] = bf16(relu(sum_ci W[co][ci]*x[b][ci][n]))
// 256 thr = 4 waves; block tile 64n x 128co, full K=128 (one shot).
// W: fp32 global -> bf16 LDS (row pad +8 -> 272B rows). x: A-frags gathered
// directly from global (16 lanes hit one 64B line), no LDS transpose.
// MFMA 16x16x32 bf16; wave w owns n-slice [n0+16w, +16), all 128 co.
// ---------------------------------------------------------------------------
__global__ __launch_bounds__(256) void gemm_relu_k(
    const float* __restrict__ x, const float* __restrict__ W,
    unsigned short* __restrict__ h) {
  __shared__ unsigned short Wl[128 * 136];  // [co][ci], +8 pad
  const int tid = threadIdx.x;
  int b, n0;
  swizzle(blockIdx.x, b, n0);

  // ---- stage W -> bf16 LDS (coalesced float4 reads, b64 LDS writes) ----
#pragma unroll
  for (int r = 0; r < 16; ++r) {
    int id = tid + 256 * r;   // 0..4095 float4s
    int co = id >> 5;
    int cq = id & 31;         // float4 index along ci
    float4 v = reinterpret_cast<const float4*>(W)[id];
    unsigned p0 = (unsigned)f2bf(v.x) | ((unsigned)f2bf(v.y) << 16);
    unsigned p1 = (unsigned)f2bf(v.z) | ((unsigned)f2bf(v.w) << 16);
    *reinterpret_cast<uint2*>(&Wl[co * 136 + 4 * cq]) = make_uint2(p0, p1);
  }
  __syncthreads();

  const int lane = tid & 63;
  const int w    = tid >> 6;
  const int m    = lane & 15;   // A: m (node) / B,D: col (co)
  const int quad = lane >> 4;

  // ---- A-fragments straight from global: a[s][j] = x[ci=32s+8q+j][n] ----
  const float* xb = x + (size_t)b * CIN_ * N_ + n0 + 16 * w + m;
  bf16x8 a[4];
#pragma unroll
  for (int s = 0; s < 4; ++s) {
#pragma unroll
    for (int j = 0; j < 8; ++j) {
      int ci = 32 * s + 8 * quad + j;
      a[s][j] = (short)f2bf(xb[(size_t)ci * N_]);
    }
  }

  const int nrow_base = n0 + 16 * w + 4 * quad;  // D row = 4*quad + reg
  unsigned short* hb = h + (size_t)b * N_ * COUT_;
#pragma unroll
  for (int t = 0; t < 8; ++t) {   // 8 co-tiles of 16
    f32x4 c = {0.f, 0.f, 0.f, 0.f};
#pragma unroll
    for (int s = 0; s < 4; ++s) { // K = 4 x 32
      bf16x8 bf = *reinterpret_cast<const bf16x8*>(
          &Wl[(16 * t + m) * 136 + 32 * s + 8 * quad]);  // 16B aligned
      c = __builtin_amdgcn_mfma_f32_16x16x32_bf16(a[s], bf, c, 0, 0, 0);
    }
    int co = 16 * t + m;
#pragma unroll
    for (int r = 0; r < 4; ++r) {
      float v = c[r] > 0.f ? c[r] : 0.f;  // ReLU
      hb[(size_t)(nrow_base + r) * COUT_ + co] = f2bf(v);
    }
  }
}

// ---------------------------------------------------------------------------
// Kernel 2: out[b][co][n] = (sum_k h[b][idx[n,k]][:] + h[b][n][:])/17 + bias
// 256 thr; tile 64n x 128co. q=tid&31 -> 4 co (8B bf16 gather: 32 lanes x 8B
// = full 256B row per half-wave), g=tid>>5 -> 8 consecutive n (-> float4
// stores along n, no LDS transpose needed). fp32 accumulate.
// ---------------------------------------------------------------------------
__global__ __launch_bounds__(256) void aggr_k(
    const unsigned short* __restrict__ h, const int* __restrict__ ei,
    const float* __restrict__ bias, float* __restrict__ out) {
  __shared__ int idx_s[64 * K_];
  const int tid = threadIdx.x;
  int b, n0;
  swizzle(blockIdx.x, b, n0);

  {  // stage neighbor indices (coalesced int4)
    const int4* src =
        reinterpret_cast<const int4*>(ei + ((size_t)b * N_ + n0) * K_);
    reinterpret_cast<int4*>(idx_s)[tid] = src[tid];
  }
  __syncthreads();

  const int q = tid & 31;   // co = 4q..4q+3
  const int g = tid >> 5;   // n_local = 8g..8g+7
  const unsigned short* hb = h + (size_t)b * N_ * COUT_;

  float acc[8][4];
#pragma unroll
  for (int j = 0; j < 8; ++j) {  // self-loop term
    uint2 v = *reinterpret_cast<const uint2*>(
        hb + (size_t)(n0 + 8 * g + j) * COUT_ + 4 * q);
    acc[j][0] = __uint_as_float(v.x << 16);
    acc[j][1] = __uint_as_float(v.x & 0xffff0000u);
    acc[j][2] = __uint_as_float(v.y << 16);
    acc[j][3] = __uint_as_float(v.y & 0xffff0000u);
  }
  for (int k = 0; k < K_; ++k) {
#pragma unroll
    for (int j = 0; j < 8; ++j) {
      int jj = idx_s[(8 * g + j) * K_ + k];  // broadcast across q-lanes
      uint2 v = *reinterpret_cast<const uint2*>(
          hb + (size_t)jj * COUT_ + 4 * q);
      acc[j][0] += __uint_as_float(v.x << 16);
      acc[j][1] += __uint_as_float(v.x & 0xffff0000u);
      acc[j][2] += __uint_as_float(v.y << 16);
      acc[j][3] += __uint_as_float(v.y & 0xffff0000u);
    }
  }

  const float norm = 1.0f / 17.0f;
  const float4 bv = *reinterpret_cast<const float4*>(bias + 4 * q);
  float* ob = out + (size_t)b * COUT_ * N_ + n0 + 8 * g;
#pragma unroll
  for (int r = 0; r < 4; ++r) {
    int co = 4 * q + r;
    float bb = (r == 0) ? bv.x : (r == 1) ? bv.y : (r == 2) ? bv.z : bv.w;
    float4 lo, hi;
    lo.x = acc[0][r] * norm + bb; lo.y = acc[1][r] * norm + bb;
    lo.z = acc[2][r] * norm + bb; lo.w = acc[3][r] * norm + bb;
    hi.x = acc[4][r] * norm + bb; hi.y = acc[5][r] * norm + bb;
    hi.z = acc[6][r] * norm + bb; hi.w = acc[7][r] * norm + bb;
    *reinterpret_cast<float4*>(ob + (size_t)co * N_)     = lo;
    *reinterpret_cast<float4*>(ob + (size_t)co * N_ + 4) = hi;
  }
}

extern "C" void kernel_launch(void* const* d_in, const int* in_sizes, int n_in,
                              void* d_out, int out_size, void* d_ws, size_t ws_size,
                              hipStream_t stream) {
  const float* x    = (const float*)d_in[0];
  const int*   ei   = (const int*)d_in[1];   // [2][B][N][K]; plane 0
  const float* W    = (const float*)d_in[2];
  const float* bias = (const float*)d_in[3];
  float* out = (float*)d_out;
  unsigned short* h = (unsigned short*)d_ws;  // B*N*COUT*2 = 16 MB bf16

  gemm_relu_k<<<dim3(B_ * N_ / 64), 256, 0, stream>>>(x, W, h);
  aggr_k<<<dim3(B_ * N_ / 64), 256, 0, stream>>>(h, ei, bias, out);
}